// Round 1
// baseline (1924.272 us; speedup 1.0000x reference)
//
#include <hip/hip_runtime.h>
#include <math.h>

#define NBATCH 2
#define LQ     19560
#define NQ     (NBATCH * LQ)      // 39120
#define DMODEL 256
#define NHEADS 8
#define HDIM   32
#define NLEV   4
#define NPTS   4

// ---------------------------------------------------------------------------
// Generic tiled fp32 GEMM: C[M,Ncols] = A[M,K] @ W[K,Ncols] (+bias) (+C if acc)
// BM=BN=64, BK=16, block 16x16, 4x4 micro-tile per thread.
// ---------------------------------------------------------------------------
__global__ __launch_bounds__(256) void gemm_tiled(
    const float* __restrict__ A, const float* __restrict__ Wm,
    const float* __restrict__ bias, float* __restrict__ C,
    int M, int K, int Ncols, int accumulate)
{
    __shared__ float As[16][65];   // +1 pad: kills 16-way bank conflict on transpose-store
    __shared__ float Bs[16][64];

    const int tx = threadIdx.x, ty = threadIdx.y;
    const int tid = ty * 16 + tx;
    const int n0 = blockIdx.x * 64;
    const int m0 = blockIdx.y * 64;

    float acc[4][4] = {};

    for (int t = 0; t < K; t += 16) {
        // load A tile (64 rows x 16 k) transposed into As[k][row]
        #pragma unroll
        for (int i = 0; i < 4; i++) {
            int idx = tid + i * 256;
            int r  = idx >> 4;          // 0..63
            int kk = idx & 15;          // 0..15
            int row = m0 + r;
            As[kk][r] = (row < M) ? A[(size_t)row * K + t + kk] : 0.0f;
        }
        // load B tile (16 k x 64 cols)
        #pragma unroll
        for (int i = 0; i < 4; i++) {
            int idx = tid + i * 256;
            int kk = idx >> 6;          // 0..15
            int c  = idx & 63;          // 0..63
            int col = n0 + c;
            Bs[kk][c] = (col < Ncols) ? Wm[(size_t)(t + kk) * Ncols + col] : 0.0f;
        }
        __syncthreads();

        #pragma unroll
        for (int kk = 0; kk < 16; kk++) {
            float a[4], b[4];
            #pragma unroll
            for (int i = 0; i < 4; i++) a[i] = As[kk][ty * 4 + i];
            #pragma unroll
            for (int j = 0; j < 4; j++) b[j] = Bs[kk][tx * 4 + j];
            #pragma unroll
            for (int i = 0; i < 4; i++)
                #pragma unroll
                for (int j = 0; j < 4; j++)
                    acc[i][j] += a[i] * b[j];
        }
        __syncthreads();
    }

    #pragma unroll
    for (int i = 0; i < 4; i++) {
        int row = m0 + ty * 4 + i;
        if (row >= M) continue;
        #pragma unroll
        for (int j = 0; j < 4; j++) {
            int col = n0 + tx * 4 + j;
            if (col >= Ncols) continue;
            float v = acc[i][j];
            if (bias) v += bias[col];
            if (accumulate) v += C[(size_t)row * Ncols + col];
            C[(size_t)row * Ncols + col] = v;
        }
    }
}

// ---------------------------------------------------------------------------
// Fused tail weights: Wf_i = W_o @ W_agg[i*256:(i+1)*256], bf = b_o@(Wagg0+Wagg1)+b_agg
// grid 256 blocks (k), 256 threads (n)
// ---------------------------------------------------------------------------
__global__ __launch_bounds__(256) void fuse_weights(
    const float* __restrict__ Wo, const float* __restrict__ Wagg,
    const float* __restrict__ bo, const float* __restrict__ bagg,
    float* __restrict__ Wf0, float* __restrict__ Wf1, float* __restrict__ bf)
{
    int n = threadIdx.x;
    int k = blockIdx.x;
    float s0 = 0.f, s1 = 0.f;
    for (int j = 0; j < 256; j++) {
        float w = Wo[k * 256 + j];
        s0 += w * Wagg[j * 256 + n];
        s1 += w * Wagg[(256 + j) * 256 + n];
    }
    Wf0[k * 256 + n] = s0;
    Wf1[k * 256 + n] = s1;
    if (k == 0) {
        float b = bagg[n];
        for (int j = 0; j < 256; j++)
            b += bo[j] * (Wagg[j * 256 + n] + Wagg[(256 + j) * 256 + n]);
        bf[n] = b;
    }
}

// ---------------------------------------------------------------------------
// Joint softmax over 32 logits per (n,q,h): [aw0 row (16) | aw1 row (16)], in-place
// ---------------------------------------------------------------------------
__global__ __launch_bounds__(256) void joint_softmax(float* __restrict__ aw0,
                                                     float* __restrict__ aw1)
{
    int r = blockIdx.x * 256 + threadIdx.x;
    if (r >= NQ * NHEADS) return;
    int nq = r >> 3, h = r & 7;
    float* p0 = aw0 + (size_t)nq * 128 + h * 16;
    float* p1 = aw1 + (size_t)nq * 128 + h * 16;
    float v[32];
    #pragma unroll
    for (int i = 0; i < 16; i++) { v[i] = p0[i]; v[16 + i] = p1[i]; }
    float m = v[0];
    #pragma unroll
    for (int i = 1; i < 32; i++) m = fmaxf(m, v[i]);
    float s = 0.f;
    #pragma unroll
    for (int i = 0; i < 32; i++) { v[i] = expf(v[i] - m); s += v[i]; }
    float inv = 1.0f / s;
    #pragma unroll
    for (int i = 0; i < 16; i++) { p0[i] = v[i] * inv; p1[i] = v[16 + i] * inv; }
}

// ---------------------------------------------------------------------------
// Deformable sampling: one block per (n,q), 256 threads = 8 heads x 32 dims.
// val: (N, Len_in, nH, 32)   off: (N,Lq,nH,L,P,2)   aw: (N,Lq,nH,L,P)
// out: (N, Lq, 256) with col = h*32+d
// ---------------------------------------------------------------------------
__global__ __launch_bounds__(256) void ms_sample(
    const float* __restrict__ val, const float* __restrict__ off,
    const float* __restrict__ aw, const float* __restrict__ refp,
    float* __restrict__ out)
{
    const int nq = blockIdx.x;           // 0..NQ-1
    const int h  = threadIdx.x >> 5;
    const int d  = threadIdx.x & 31;
    const int n  = nq / LQ;

    __shared__ float rp[NLEV * 2];
    if (threadIdx.x < NLEV * 2) rp[threadIdx.x] = refp[(size_t)nq * (NLEV * 2) + threadIdx.x];
    __syncthreads();

    const int Hs[4] = {92, 46, 23, 12};
    const int Ws[4] = {160, 80, 40, 20};
    const int Ss[4] = {0, 14720, 18400, 19320};

    const size_t obase = ((size_t)nq * NHEADS + h) * (NLEV * NPTS);  // per-(nq,h) point base
    float acc = 0.0f;

    #pragma unroll
    for (int l = 0; l < NLEV; l++) {
        const int H = Hs[l], W = Ws[l];
        const float* vb = val + ((size_t)(n * LQ + Ss[l])) * DMODEL + h * HDIM + d;
        const float rx = rp[l * 2 + 0];
        const float ry = rp[l * 2 + 1];
        #pragma unroll
        for (int p = 0; p < NPTS; p++) {
            const int pi = l * NPTS + p;
            const float ox = off[(obase + pi) * 2 + 0];
            const float oy = off[(obase + pi) * 2 + 1];
            const float a  = aw[obase + pi];
            // loc = ref + off/normalizer; x = loc*W - 0.5 (ref op order)
            const float lx = rx + ox / (float)W;
            const float ly = ry + oy / (float)H;
            const float x = lx * (float)W - 0.5f;
            const float y = ly * (float)H - 0.5f;
            const float x0f = floorf(x), y0f = floorf(y);
            const int x0 = (int)x0f, y0 = (int)y0f;
            const float wx1 = x - x0f;          // (x - x0)
            const float wx0 = x0f + 1.0f - x;   // (x0+1 - x)
            const float wy1 = y - y0f;
            const float wy0 = y0f + 1.0f - y;

            float s = 0.0f;
            const bool xin0 = (x0 >= 0) && (x0 <= W - 1);
            const bool xin1 = (x0 + 1 >= 0) && (x0 + 1 <= W - 1);
            const bool yin0 = (y0 >= 0) && (y0 <= H - 1);
            const bool yin1 = (y0 + 1 >= 0) && (y0 + 1 <= H - 1);
            if (yin0 && xin0) s += wy0 * wx0 * vb[(size_t)(y0 * W + x0) * DMODEL];
            if (yin0 && xin1) s += wy0 * wx1 * vb[(size_t)(y0 * W + x0 + 1) * DMODEL];
            if (yin1 && xin0) s += wy1 * wx0 * vb[(size_t)((y0 + 1) * W + x0) * DMODEL];
            if (yin1 && xin1) s += wy1 * wx1 * vb[(size_t)((y0 + 1) * W + x0 + 1) * DMODEL];
            acc += a * s;
        }
    }
    out[(size_t)nq * DMODEL + h * HDIM + d] = acc;
}

// ---------------------------------------------------------------------------
extern "C" void kernel_launch(void* const* d_in, const int* in_sizes, int n_in,
                              void* d_out, int out_size, void* d_ws, size_t ws_size,
                              hipStream_t stream)
{
    const float* q0    = (const float*)d_in[0];
    const float* q1    = (const float*)d_in[1];
    const float* refp  = (const float*)d_in[2];
    const float* f0    = (const float*)d_in[3];
    const float* f1    = (const float*)d_in[4];
    // d_in[5]/d_in[6]: spatial shapes / level starts — fixed, hardcoded
    const float* W_so  = (const float*)d_in[7];
    const float* b_so  = (const float*)d_in[8];
    const float* W_aw  = (const float*)d_in[9];
    const float* b_aw  = (const float*)d_in[10];
    const float* W_v   = (const float*)d_in[11];
    const float* b_v   = (const float*)d_in[12];
    const float* W_o   = (const float*)d_in[13];
    const float* b_o   = (const float*)d_in[14];
    const float* W_agg = (const float*)d_in[15];
    const float* b_agg = (const float*)d_in[16];
    float* out = (float*)d_out;

    float* ws     = (float*)d_ws;
    float* bufV   = ws;                              // NQ*256
    float* bufOff = bufV   + (size_t)NQ * 256;       // NQ*256
    float* bufO   = bufOff + (size_t)NQ * 256;       // NQ*256
    float* aw0    = bufO   + (size_t)NQ * 256;       // NQ*128
    float* aw1    = aw0    + (size_t)NQ * 128;       // NQ*128
    float* Wf0    = aw1    + (size_t)NQ * 128;       // 65536
    float* Wf1    = Wf0    + 65536;                  // 65536
    float* bf     = Wf1    + 65536;                  // 256

    dim3 blk(16, 16);
    dim3 g256((256 + 63) / 64, (NQ + 63) / 64);
    dim3 g128((128 + 63) / 64, (NQ + 63) / 64);

    // attention-weight logits + joint softmax
    gemm_tiled<<<g128, blk, 0, stream>>>(q0, W_aw, b_aw, aw0, NQ, 256, 128, 0);
    gemm_tiled<<<g128, blk, 0, stream>>>(q1, W_aw, b_aw, aw1, NQ, 256, 128, 0);
    joint_softmax<<<(NQ * NHEADS + 255) / 256, 256, 0, stream>>>(aw0, aw1);

    // fused tail weights
    fuse_weights<<<256, 256, 0, stream>>>(W_o, W_agg, b_o, b_agg, Wf0, Wf1, bf);

    // iter 0
    gemm_tiled<<<g256, blk, 0, stream>>>(f0, W_v, b_v, bufV, NQ, 256, 256, 0);
    gemm_tiled<<<g256, blk, 0, stream>>>(q0, W_so, b_so, bufOff, NQ, 256, 256, 0);
    ms_sample<<<NQ, 256, 0, stream>>>(bufV, bufOff, aw0, refp, bufO);
    gemm_tiled<<<g256, blk, 0, stream>>>(bufO, Wf0, bf, out, NQ, 256, 256, 0);

    // iter 1
    gemm_tiled<<<g256, blk, 0, stream>>>(f1, W_v, b_v, bufV, NQ, 256, 256, 0);
    gemm_tiled<<<g256, blk, 0, stream>>>(q1, W_so, b_so, bufOff, NQ, 256, 256, 0);
    ms_sample<<<NQ, 256, 0, stream>>>(bufV, bufOff, aw1, refp, bufO);
    gemm_tiled<<<g256, blk, 0, stream>>>(bufO, Wf1, nullptr, out, NQ, 256, 256, 1);
}

// Round 2
// 1382.433 us; speedup vs baseline: 1.3919x; 1.3919x over previous
//
#include <hip/hip_runtime.h>
#include <math.h>

#define NBATCH 2
#define LQ     19560
#define NQ     (NBATCH * LQ)      // 39120
#define DMODEL 256
#define NHEADS 8
#define HDIM   32
#define NLEV   4
#define NPTS   4

// ---------------------------------------------------------------------------
// Tiled fp32 GEMM: C[M,Ncols] = A[M,K] @ W[K,Ncols] (+bias) (+C if acc)
// BM=BN=128, BK=16, 256 threads, 8x8 micro-tile per thread, float4 loads.
// Requires: K % 16 == 0, Ncols % 128 == 0. M guarded.
// LDS: As transposed with stride 132 (2-way conflicts only -> free).
// ---------------------------------------------------------------------------
#define ASTRIDE 132
__global__ __launch_bounds__(256) void gemm_tiled(
    const float* __restrict__ A, const float* __restrict__ Wm,
    const float* __restrict__ bias, float* __restrict__ C,
    int M, int K, int Ncols, int accumulate)
{
    __shared__ float As[16][ASTRIDE];  // [k][m], padded
    __shared__ float Bs[16][128];      // [k][n]

    const int tid = threadIdx.x;
    const int tx = tid & 15;
    const int ty = tid >> 4;
    const int n0 = blockIdx.x * 128;
    const int m0 = blockIdx.y * 128;

    float acc[8][8] = {};

    for (int t = 0; t < K; t += 16) {
        // A tile: 128 rows x 16 k = 512 float4; thread handles v = tid, tid+256
        #pragma unroll
        for (int i = 0; i < 2; i++) {
            int v = tid + i * 256;
            int r = v >> 2;            // 0..127
            int kq = v & 3;            // k-quad
            int row = m0 + r;
            float4 a4 = make_float4(0.f, 0.f, 0.f, 0.f);
            if (row < M) a4 = *(const float4*)&A[(size_t)row * K + t + kq * 4];
            As[kq * 4 + 0][r] = a4.x;
            As[kq * 4 + 1][r] = a4.y;
            As[kq * 4 + 2][r] = a4.z;
            As[kq * 4 + 3][r] = a4.w;
        }
        // B tile: 16 k x 128 n = 512 float4
        #pragma unroll
        for (int i = 0; i < 2; i++) {
            int v = tid + i * 256;
            int kk = v >> 5;           // 0..15
            int cq = v & 31;           // col-quad
            *(float4*)&Bs[kk][cq * 4] =
                *(const float4*)&Wm[(size_t)(t + kk) * Ncols + n0 + cq * 4];
        }
        __syncthreads();

        #pragma unroll
        for (int kk = 0; kk < 16; kk++) {
            float a[8], b[8];
            *(float4*)&a[0] = *(const float4*)&As[kk][ty * 4];
            *(float4*)&a[4] = *(const float4*)&As[kk][ty * 4 + 64];
            *(float4*)&b[0] = *(const float4*)&Bs[kk][tx * 4];
            *(float4*)&b[4] = *(const float4*)&Bs[kk][tx * 4 + 64];
            #pragma unroll
            for (int i = 0; i < 8; i++)
                #pragma unroll
                for (int j = 0; j < 8; j++)
                    acc[i][j] += a[i] * b[j];
        }
        __syncthreads();
    }

    #pragma unroll
    for (int ii = 0; ii < 2; ii++) {
        #pragma unroll
        for (int i = 0; i < 4; i++) {
            int row = m0 + ii * 64 + ty * 4 + i;
            if (row >= M) continue;
            #pragma unroll
            for (int jj = 0; jj < 2; jj++) {
                int col = n0 + jj * 64 + tx * 4;
                float4 v;
                v.x = acc[ii * 4 + i][jj * 4 + 0];
                v.y = acc[ii * 4 + i][jj * 4 + 1];
                v.z = acc[ii * 4 + i][jj * 4 + 2];
                v.w = acc[ii * 4 + i][jj * 4 + 3];
                if (bias) {
                    float4 b4 = *(const float4*)&bias[col];
                    v.x += b4.x; v.y += b4.y; v.z += b4.z; v.w += b4.w;
                }
                float* cp = &C[(size_t)row * Ncols + col];
                if (accumulate) {
                    float4 c4 = *(const float4*)cp;
                    v.x += c4.x; v.y += c4.y; v.z += c4.z; v.w += c4.w;
                }
                *(float4*)cp = v;
            }
        }
    }
}

// ---------------------------------------------------------------------------
// Fused tail weights: Wf_i = W_o @ W_agg[i*256:(i+1)*256], bf = b_o@(Wagg0+Wagg1)+b_agg
// ---------------------------------------------------------------------------
__global__ __launch_bounds__(256) void fuse_weights(
    const float* __restrict__ Wo, const float* __restrict__ Wagg,
    const float* __restrict__ bo, const float* __restrict__ bagg,
    float* __restrict__ Wf0, float* __restrict__ Wf1, float* __restrict__ bf)
{
    int n = threadIdx.x;
    int k = blockIdx.x;
    float s0 = 0.f, s1 = 0.f;
    for (int j = 0; j < 256; j++) {
        float w = Wo[k * 256 + j];
        s0 += w * Wagg[j * 256 + n];
        s1 += w * Wagg[(256 + j) * 256 + n];
    }
    Wf0[k * 256 + n] = s0;
    Wf1[k * 256 + n] = s1;
    if (k == 0) {
        float b = bagg[n];
        for (int j = 0; j < 256; j++)
            b += bo[j] * (Wagg[j * 256 + n] + Wagg[(256 + j) * 256 + n]);
        bf[n] = b;
    }
}

// ---------------------------------------------------------------------------
// Joint softmax over 32 logits per (n,q,h): [aw0 row (16) | aw1 row (16)], in-place
// ---------------------------------------------------------------------------
__global__ __launch_bounds__(256) void joint_softmax(float* __restrict__ aw0,
                                                     float* __restrict__ aw1)
{
    int r = blockIdx.x * 256 + threadIdx.x;
    if (r >= NQ * NHEADS) return;
    int nq = r >> 3, h = r & 7;
    float* p0 = aw0 + (size_t)nq * 128 + h * 16;
    float* p1 = aw1 + (size_t)nq * 128 + h * 16;
    float v[32];
    #pragma unroll
    for (int i = 0; i < 16; i++) { v[i] = p0[i]; v[16 + i] = p1[i]; }
    float m = v[0];
    #pragma unroll
    for (int i = 1; i < 32; i++) m = fmaxf(m, v[i]);
    float s = 0.f;
    #pragma unroll
    for (int i = 0; i < 32; i++) { v[i] = expf(v[i] - m); s += v[i]; }
    float inv = 1.0f / s;
    #pragma unroll
    for (int i = 0; i < 16; i++) { p0[i] = v[i] * inv; p1[i] = v[16 + i] * inv; }
}

// ---------------------------------------------------------------------------
// Deformable sampling: 4 queries per block; 64 threads/query = 8 heads x 8 lanes;
// each lane owns 4 dims (float4 gathers).
// val: (N, Len_in, nH, 32)   off: (N,Lq,nH,L,P,2)   aw: (N,Lq,nH,L,P)
// out: (N, Lq, 256) with col = h*32+d
// ---------------------------------------------------------------------------
__global__ __launch_bounds__(256) void ms_sample(
    const float* __restrict__ val, const float* __restrict__ off,
    const float* __restrict__ aw, const float* __restrict__ refp,
    float* __restrict__ out)
{
    const int tid = threadIdx.x;
    const int qi = tid >> 6;            // 0..3
    const int h  = (tid >> 3) & 7;      // head
    const int dl = (tid & 7) * 4;       // dim offset (float4)
    const int nq = blockIdx.x * 4 + qi; // NQ % 4 == 0
    const int n  = nq / LQ;

    const int Hs[4] = {92, 46, 23, 12};
    const int Ws[4] = {160, 80, 40, 20};
    const int Ss[4] = {0, 14720, 18400, 19320};

    const size_t obase = ((size_t)nq * NHEADS + h) * (NLEV * NPTS);
    const float* rpq = refp + (size_t)nq * (NLEV * 2);

    float ax = 0.f, ay = 0.f, az = 0.f, aw_ = 0.f;

    #pragma unroll
    for (int l = 0; l < NLEV; l++) {
        const int H = Hs[l], W = Ws[l];
        const float* vb = val + ((size_t)(n * LQ + Ss[l])) * DMODEL + h * HDIM + dl;
        const float rx = rpq[l * 2 + 0];
        const float ry = rpq[l * 2 + 1];
        #pragma unroll
        for (int p = 0; p < NPTS; p++) {
            const int pi = l * NPTS + p;
            const float ox = off[(obase + pi) * 2 + 0];
            const float oy = off[(obase + pi) * 2 + 1];
            const float a  = aw[obase + pi];
            // ref op order: loc = ref + off/normalizer; x = loc*W - 0.5
            const float lx = rx + ox / (float)W;
            const float ly = ry + oy / (float)H;
            const float x = lx * (float)W - 0.5f;
            const float y = ly * (float)H - 0.5f;
            const float x0f = floorf(x), y0f = floorf(y);
            const int x0 = (int)x0f, y0 = (int)y0f;
            const float wx1 = x - x0f;
            const float wx0 = x0f + 1.0f - x;
            const float wy1 = y - y0f;
            const float wy0 = y0f + 1.0f - y;

            const bool xin0 = (x0 >= 0) && (x0 < W);
            const bool xin1 = (x0 + 1 >= 0) && (x0 + 1 < W);
            const bool yin0 = (y0 >= 0) && (y0 < H);
            const bool yin1 = (y0 + 1 >= 0) && (y0 + 1 < H);

            float sx = 0.f, sy = 0.f, sz = 0.f, sw = 0.f;
            if (yin0 && xin0) {
                float4 c = *(const float4*)(vb + (size_t)(y0 * W + x0) * DMODEL);
                float w0 = wy0 * wx0;
                sx += w0 * c.x; sy += w0 * c.y; sz += w0 * c.z; sw += w0 * c.w;
            }
            if (yin0 && xin1) {
                float4 c = *(const float4*)(vb + (size_t)(y0 * W + x0 + 1) * DMODEL);
                float w1 = wy0 * wx1;
                sx += w1 * c.x; sy += w1 * c.y; sz += w1 * c.z; sw += w1 * c.w;
            }
            if (yin1 && xin0) {
                float4 c = *(const float4*)(vb + (size_t)((y0 + 1) * W + x0) * DMODEL);
                float w2 = wy1 * wx0;
                sx += w2 * c.x; sy += w2 * c.y; sz += w2 * c.z; sw += w2 * c.w;
            }
            if (yin1 && xin1) {
                float4 c = *(const float4*)(vb + (size_t)((y0 + 1) * W + x0 + 1) * DMODEL);
                float w3 = wy1 * wx1;
                sx += w3 * c.x; sy += w3 * c.y; sz += w3 * c.z; sw += w3 * c.w;
            }
            ax += a * sx; ay += a * sy; az += a * sz; aw_ += a * sw;
        }
    }
    float* op = out + (size_t)nq * DMODEL + h * HDIM + dl;
    float4 r; r.x = ax; r.y = ay; r.z = az; r.w = aw_;
    *(float4*)op = r;
}

// ---------------------------------------------------------------------------
extern "C" void kernel_launch(void* const* d_in, const int* in_sizes, int n_in,
                              void* d_out, int out_size, void* d_ws, size_t ws_size,
                              hipStream_t stream)
{
    const float* q0    = (const float*)d_in[0];
    const float* q1    = (const float*)d_in[1];
    const float* refp  = (const float*)d_in[2];
    const float* f0    = (const float*)d_in[3];
    const float* f1    = (const float*)d_in[4];
    // d_in[5]/d_in[6]: spatial shapes / level starts — fixed, hardcoded
    const float* W_so  = (const float*)d_in[7];
    const float* b_so  = (const float*)d_in[8];
    const float* W_aw  = (const float*)d_in[9];
    const float* b_aw  = (const float*)d_in[10];
    const float* W_v   = (const float*)d_in[11];
    const float* b_v   = (const float*)d_in[12];
    const float* W_o   = (const float*)d_in[13];
    const float* b_o   = (const float*)d_in[14];
    const float* W_agg = (const float*)d_in[15];
    const float* b_agg = (const float*)d_in[16];
    float* out = (float*)d_out;

    float* ws     = (float*)d_ws;
    float* bufV   = ws;                              // NQ*256
    float* bufOff = bufV   + (size_t)NQ * 256;       // NQ*256
    float* bufO   = bufOff + (size_t)NQ * 256;       // NQ*256
    float* aw0    = bufO   + (size_t)NQ * 256;       // NQ*128
    float* aw1    = aw0    + (size_t)NQ * 128;       // NQ*128
    float* Wf0    = aw1    + (size_t)NQ * 128;       // 65536
    float* Wf1    = Wf0    + 65536;                  // 65536
    float* bf     = Wf1    + 65536;                  // 256

    dim3 blk(256);
    dim3 g256(256 / 128, (NQ + 127) / 128);
    dim3 g128(128 / 128, (NQ + 127) / 128);

    // attention-weight logits + joint softmax
    gemm_tiled<<<g128, blk, 0, stream>>>(q0, W_aw, b_aw, aw0, NQ, 256, 128, 0);
    gemm_tiled<<<g128, blk, 0, stream>>>(q1, W_aw, b_aw, aw1, NQ, 256, 128, 0);
    joint_softmax<<<(NQ * NHEADS + 255) / 256, 256, 0, stream>>>(aw0, aw1);

    // fused tail weights
    fuse_weights<<<256, 256, 0, stream>>>(W_o, W_agg, b_o, b_agg, Wf0, Wf1, bf);

    // iter 0
    gemm_tiled<<<g256, blk, 0, stream>>>(f0, W_v, b_v, bufV, NQ, 256, 256, 0);
    gemm_tiled<<<g256, blk, 0, stream>>>(q0, W_so, b_so, bufOff, NQ, 256, 256, 0);
    ms_sample<<<NQ / 4, 256, 0, stream>>>(bufV, bufOff, aw0, refp, bufO);
    gemm_tiled<<<g256, blk, 0, stream>>>(bufO, Wf0, bf, out, NQ, 256, 256, 0);

    // iter 1
    gemm_tiled<<<g256, blk, 0, stream>>>(f1, W_v, b_v, bufV, NQ, 256, 256, 0);
    gemm_tiled<<<g256, blk, 0, stream>>>(q1, W_so, b_so, bufOff, NQ, 256, 256, 0);
    ms_sample<<<NQ / 4, 256, 0, stream>>>(bufV, bufOff, aw1, refp, bufO);
    gemm_tiled<<<g256, blk, 0, stream>>>(bufO, Wf1, nullptr, out, NQ, 256, 256, 1);
}

// Round 3
// 961.512 us; speedup vs baseline: 2.0013x; 1.4378x over previous
//
#include <hip/hip_runtime.h>
#include <math.h>

#define NBATCH 2
#define LQ     19560
#define NQ     (NBATCH * LQ)      // 39120
#define DMODEL 256
#define NHEADS 8
#define HDIM   32
#define NLEV   4
#define NPTS   4

typedef __bf16 bf16x8 __attribute__((ext_vector_type(8)));
typedef float  f32x4  __attribute__((ext_vector_type(4)));

__device__ inline float bf2f(unsigned short u) {
    return __uint_as_float(((unsigned int)u) << 16);
}
__device__ inline unsigned short f2bf(float f) {
    unsigned int u = __float_as_uint(f);
    u += 0x7FFFu + ((u >> 16) & 1u);     // round-to-nearest-even
    return (unsigned short)(u >> 16);
}

// ---------------------------------------------------------------------------
// bf16 MFMA GEMM: C[M,N] = A_fp32[M,K] (cvt to bf16 in staging) @ Bt_bf16[N,K]^T
// 128x128 tile, BK=64, 256 threads = 4 waves (2x2 of 64x64), 4x4 16x16x32 MFMA.
// mode: 0 = store fp32 (+bias), 1 = accumulate fp32 (+bias), 2 = store bf16 (+bias)
// Fragment layouts (m89/m120-verified): A[m=lane&15][k=quad*8+j],
// B[k=quad*8+j][n=lane&15], D[row=quad*4+reg][col=lane&15].
// ---------------------------------------------------------------------------
#define LDK 72   // padded row stride (bf16): 144 B = 9 quads -> balanced b128 banks

__global__ __launch_bounds__(256) void gemm_bf16(
    const float* __restrict__ A, const unsigned short* __restrict__ Bt,
    const float* __restrict__ bias, void* __restrict__ Cv,
    int M, int K, int N, int mode)
{
    __shared__ unsigned short As[128 * LDK];
    __shared__ unsigned short Bs[128 * LDK];

    const int tid  = threadIdx.x;
    const int wave = tid >> 6, lane = tid & 63;
    const int wm = wave >> 1, wn = wave & 1;
    const int m0 = blockIdx.y * 128, n0 = blockIdx.x * 128;
    const int lr = lane & 15, quad = lane >> 4;

    const f32x4 zero = {0.f, 0.f, 0.f, 0.f};
    f32x4 acc[4][4];
    #pragma unroll
    for (int i = 0; i < 4; i++)
        #pragma unroll
        for (int j = 0; j < 4; j++) acc[i][j] = zero;

    for (int t = 0; t < K; t += 64) {
        // stage A (convert fp32 -> bf16): 128 rows x 64 k, 8-float chunks
        #pragma unroll
        for (int i = 0; i < 4; i++) {
            int v = tid + i * 256;
            int r = v >> 3, c = v & 7;
            int row = m0 + r;
            union { uint4 u; unsigned short s[8]; } tmp;
            if (row < M) {
                const float* ap = &A[(size_t)row * K + t + c * 8];
                float4 x = *(const float4*)ap;
                float4 y = *(const float4*)(ap + 4);
                tmp.s[0] = f2bf(x.x); tmp.s[1] = f2bf(x.y);
                tmp.s[2] = f2bf(x.z); tmp.s[3] = f2bf(x.w);
                tmp.s[4] = f2bf(y.x); tmp.s[5] = f2bf(y.y);
                tmp.s[6] = f2bf(y.z); tmp.s[7] = f2bf(y.w);
            } else {
                tmp.u = make_uint4(0, 0, 0, 0);
            }
            *(uint4*)&As[r * LDK + c * 8] = tmp.u;
        }
        // stage Bt (already bf16): 128 rows x 64 k
        #pragma unroll
        for (int i = 0; i < 4; i++) {
            int v = tid + i * 256;
            int r = v >> 3, c = v & 7;
            uint4 d = make_uint4(0, 0, 0, 0);
            if (n0 + r < N) d = *(const uint4*)&Bt[(size_t)(n0 + r) * K + t + c * 8];
            *(uint4*)&Bs[r * LDK + c * 8] = d;
        }
        __syncthreads();

        #pragma unroll
        for (int kk = 0; kk < 2; kk++) {
            bf16x8 af[4], bff[4];
            #pragma unroll
            for (int mi = 0; mi < 4; mi++)
                af[mi] = *(const bf16x8*)&As[(wm * 64 + mi * 16 + lr) * LDK + kk * 32 + quad * 8];
            #pragma unroll
            for (int ni = 0; ni < 4; ni++)
                bff[ni] = *(const bf16x8*)&Bs[(wn * 64 + ni * 16 + lr) * LDK + kk * 32 + quad * 8];
            #pragma unroll
            for (int mi = 0; mi < 4; mi++)
                #pragma unroll
                for (int ni = 0; ni < 4; ni++)
                    acc[mi][ni] = __builtin_amdgcn_mfma_f32_16x16x32_bf16(
                        af[mi], bff[ni], acc[mi][ni], 0, 0, 0);
        }
        __syncthreads();
    }

    float* Cf = (float*)Cv;
    unsigned short* Cb = (unsigned short*)Cv;
    #pragma unroll
    for (int mi = 0; mi < 4; mi++) {
        #pragma unroll
        for (int reg = 0; reg < 4; reg++) {
            int row = m0 + wm * 64 + mi * 16 + quad * 4 + reg;
            if (row >= M) continue;
            #pragma unroll
            for (int ni = 0; ni < 4; ni++) {
                int col = n0 + wn * 64 + ni * 16 + lr;
                float v = acc[mi][ni][reg];
                if (bias) v += bias[col];
                size_t o = (size_t)row * N + col;
                if (mode == 0) Cf[o] = v;
                else if (mode == 1) Cf[o] += v;
                else Cb[o] = f2bf(v);
            }
        }
    }
}

// ---------------------------------------------------------------------------
// Weight transpose+convert: outw[n*K + k] = bf16(in[k*N + n]); K == 256.
// ---------------------------------------------------------------------------
__global__ __launch_bounds__(256) void wt_conv(const float* __restrict__ in,
                                               unsigned short* __restrict__ outw,
                                               int K, int N)
{
    int o = blockIdx.x * 256 + threadIdx.x;  // o = n*K + k
    if (o >= K * N) return;
    int k = o & 255;
    int n = o >> 8;
    outw[o] = f2bf(in[(size_t)k * N + n]);
}

// ---------------------------------------------------------------------------
// Fused tail weights (transposed bf16): Wf_i^T[n][k] = (W_o @ W_agg_half_i)[k][n]
// bf = b_o @ (Wagg0 + Wagg1) + b_agg  (fp32)
// ---------------------------------------------------------------------------
__global__ __launch_bounds__(256) void fuse_weights(
    const float* __restrict__ Wo, const float* __restrict__ Wagg,
    const float* __restrict__ bo, const float* __restrict__ bagg,
    unsigned short* __restrict__ Wf0t, unsigned short* __restrict__ Wf1t,
    float* __restrict__ bf)
{
    int n = threadIdx.x;
    int k = blockIdx.x;
    float s0 = 0.f, s1 = 0.f;
    for (int j = 0; j < 256; j++) {
        float w = Wo[k * 256 + j];
        s0 += w * Wagg[j * 256 + n];
        s1 += w * Wagg[(256 + j) * 256 + n];
    }
    Wf0t[(size_t)n * 256 + k] = f2bf(s0);
    Wf1t[(size_t)n * 256 + k] = f2bf(s1);
    if (k == 0) {
        float b = bagg[n];
        for (int j = 0; j < 256; j++)
            b += bo[j] * (Wagg[j * 256 + n] + Wagg[(256 + j) * 256 + n]);
        bf[n] = b;
    }
}

// ---------------------------------------------------------------------------
// Joint softmax over 32 logits per (n,q,h): [aw0 row (16) | aw1 row (16)], in-place
// ---------------------------------------------------------------------------
__global__ __launch_bounds__(256) void joint_softmax(float* __restrict__ aw0,
                                                     float* __restrict__ aw1)
{
    int r = blockIdx.x * 256 + threadIdx.x;
    if (r >= NQ * NHEADS) return;
    int nq = r >> 3, h = r & 7;
    float* p0 = aw0 + (size_t)nq * 128 + h * 16;
    float* p1 = aw1 + (size_t)nq * 128 + h * 16;
    float v[32];
    #pragma unroll
    for (int i = 0; i < 16; i++) { v[i] = p0[i]; v[16 + i] = p1[i]; }
    float m = v[0];
    #pragma unroll
    for (int i = 1; i < 32; i++) m = fmaxf(m, v[i]);
    float s = 0.f;
    #pragma unroll
    for (int i = 0; i < 32; i++) { v[i] = expf(v[i] - m); s += v[i]; }
    float inv = 1.0f / s;
    #pragma unroll
    for (int i = 0; i < 16; i++) { p0[i] = v[i] * inv; p1[i] = v[16 + i] * inv; }
}

// ---------------------------------------------------------------------------
// Deformable sampling on bf16 values: 8 queries/block; 32 threads/query =
// 8 heads x 4 lanes; each lane owns 8 dims (one uint4 = 8 bf16 per gather).
// val: bf16 (N, Len_in, 8, 32); off fp32 (N,Lq,8,L,P,2); aw fp32 (N,Lq,8,L,P)
// out: fp32 (N, Lq, 256), col = h*32+d
// ---------------------------------------------------------------------------
__global__ __launch_bounds__(256) void ms_sample(
    const unsigned short* __restrict__ val, const float* __restrict__ off,
    const float* __restrict__ aw, const float* __restrict__ refp,
    float* __restrict__ out)
{
    const int tid  = threadIdx.x;
    const int qi   = tid >> 5;           // 0..7
    const int lane = tid & 31;
    const int h    = lane >> 2;
    const int dl   = (lane & 3) * 8;     // 8 dims per lane
    const int nq   = blockIdx.x * 8 + qi;
    const int n    = nq / LQ;

    const int Hs[4] = {92, 46, 23, 12};
    const int Ws[4] = {160, 80, 40, 20};
    const int Ss[4] = {0, 14720, 18400, 19320};

    const size_t obase = ((size_t)nq * NHEADS + h) * 16;
    const float* rpq = refp + (size_t)nq * 8;

    float acc[8] = {0.f, 0.f, 0.f, 0.f, 0.f, 0.f, 0.f, 0.f};

    #pragma unroll
    for (int l = 0; l < NLEV; l++) {
        const int H = Hs[l], W = Ws[l];
        const unsigned short* vb = val + ((size_t)(n * LQ + Ss[l])) * DMODEL + h * HDIM + dl;
        const float rx = rpq[l * 2 + 0];
        const float ry = rpq[l * 2 + 1];
        float4 o0 = *(const float4*)&off[(obase + l * 4) * 2];
        float4 o1 = *(const float4*)&off[(obase + l * 4) * 2 + 4];
        float4 a4 = *(const float4*)&aw[obase + l * 4];
        float oxs[4] = {o0.x, o0.z, o1.x, o1.z};
        float oys[4] = {o0.y, o0.w, o1.y, o1.w};
        float avs[4] = {a4.x, a4.y, a4.z, a4.w};
        #pragma unroll
        for (int p = 0; p < NPTS; p++) {
            const float a = avs[p];
            // ref op order: loc = ref + off/normalizer; x = loc*W - 0.5
            const float lx = rx + oxs[p] / (float)W;
            const float ly = ry + oys[p] / (float)H;
            const float x = lx * (float)W - 0.5f;
            const float y = ly * (float)H - 0.5f;
            const float x0f = floorf(x), y0f = floorf(y);
            const int x0 = (int)x0f, y0 = (int)y0f;
            const float wx1 = x - x0f;
            const float wx0 = x0f + 1.0f - x;
            const float wy1 = y - y0f;
            const float wy0 = y0f + 1.0f - y;

            const bool xin0 = (x0 >= 0) && (x0 < W);
            const bool xin1 = (x0 + 1 >= 0) && (x0 + 1 < W);
            const bool yin0 = (y0 >= 0) && (y0 < H);
            const bool yin1 = (y0 + 1 >= 0) && (y0 + 1 < H);

            float s[8] = {0.f, 0.f, 0.f, 0.f, 0.f, 0.f, 0.f, 0.f};
            if (yin0 && xin0) {
                uint4 c = *(const uint4*)(vb + (size_t)(y0 * W + x0) * DMODEL);
                const unsigned short* u = (const unsigned short*)&c;
                const float w0 = wy0 * wx0;
                #pragma unroll
                for (int e = 0; e < 8; e++) s[e] += w0 * bf2f(u[e]);
            }
            if (yin0 && xin1) {
                uint4 c = *(const uint4*)(vb + (size_t)(y0 * W + x0 + 1) * DMODEL);
                const unsigned short* u = (const unsigned short*)&c;
                const float w1 = wy0 * wx1;
                #pragma unroll
                for (int e = 0; e < 8; e++) s[e] += w1 * bf2f(u[e]);
            }
            if (yin1 && xin0) {
                uint4 c = *(const uint4*)(vb + (size_t)((y0 + 1) * W + x0) * DMODEL);
                const unsigned short* u = (const unsigned short*)&c;
                const float w2 = wy1 * wx0;
                #pragma unroll
                for (int e = 0; e < 8; e++) s[e] += w2 * bf2f(u[e]);
            }
            if (yin1 && xin1) {
                uint4 c = *(const uint4*)(vb + (size_t)((y0 + 1) * W + x0 + 1) * DMODEL);
                const unsigned short* u = (const unsigned short*)&c;
                const float w3 = wy1 * wx1;
                #pragma unroll
                for (int e = 0; e < 8; e++) s[e] += w3 * bf2f(u[e]);
            }
            #pragma unroll
            for (int e = 0; e < 8; e++) acc[e] += a * s[e];
        }
    }
    float* op = out + (size_t)nq * DMODEL + h * HDIM + dl;
    float4 r0, r1;
    r0.x = acc[0]; r0.y = acc[1]; r0.z = acc[2]; r0.w = acc[3];
    r1.x = acc[4]; r1.y = acc[5]; r1.z = acc[6]; r1.w = acc[7];
    *(float4*)op = r0;
    *(float4*)(op + 4) = r1;
}

// ---------------------------------------------------------------------------
extern "C" void kernel_launch(void* const* d_in, const int* in_sizes, int n_in,
                              void* d_out, int out_size, void* d_ws, size_t ws_size,
                              hipStream_t stream)
{
    const float* q0    = (const float*)d_in[0];
    const float* q1    = (const float*)d_in[1];
    const float* refp  = (const float*)d_in[2];
    const float* f0    = (const float*)d_in[3];
    const float* f1    = (const float*)d_in[4];
    // d_in[5]/d_in[6]: spatial shapes / level starts — fixed, hardcoded
    const float* W_so  = (const float*)d_in[7];
    const float* b_so  = (const float*)d_in[8];
    const float* W_aw  = (const float*)d_in[9];
    const float* b_aw  = (const float*)d_in[10];
    const float* W_v   = (const float*)d_in[11];
    const float* b_v   = (const float*)d_in[12];
    const float* W_o   = (const float*)d_in[13];
    const float* b_o   = (const float*)d_in[14];
    const float* W_agg = (const float*)d_in[15];
    const float* b_agg = (const float*)d_in[16];
    float* out = (float*)d_out;

    float* ws = (float*)d_ws;
    unsigned short* bufVb = (unsigned short*)ws;            // NQ*256 bf16 (128*NQ fl)
    float* bufOff = ws + (size_t)NQ * 128;                  // NQ*256 fl
    float* bufO   = bufOff + (size_t)NQ * 256;              // NQ*256 fl
    float* aw0    = bufO   + (size_t)NQ * 256;              // NQ*128 fl
    float* aw1    = aw0    + (size_t)NQ * 128;              // NQ*128 fl
    float* wtail  = aw1    + (size_t)NQ * 128;
    unsigned short* Wvt  = (unsigned short*)wtail;          // 65536 ush
    unsigned short* Wsot = Wvt  + 65536;                    // 65536 ush
    unsigned short* Wawt = Wsot + 65536;                    // 32768 ush
    unsigned short* Wf0t = Wawt + 32768;                    // 65536 ush
    unsigned short* Wf1t = Wf0t + 65536;                    // 65536 ush
    float* bf = (float*)(Wf1t + 65536);                     // 256 fl

    const int MB = (NQ + 127) / 128;   // 306
    dim3 blk(256);
    dim3 g256(2, MB);
    dim3 g128(1, MB);

    // weight preps
    wt_conv<<<(65536 + 255) / 256, 256, 0, stream>>>(W_v,  Wvt,  256, 256);
    wt_conv<<<(65536 + 255) / 256, 256, 0, stream>>>(W_so, Wsot, 256, 256);
    wt_conv<<<(32768 + 255) / 256, 256, 0, stream>>>(W_aw, Wawt, 256, 128);
    fuse_weights<<<256, 256, 0, stream>>>(W_o, W_agg, b_o, b_agg, Wf0t, Wf1t, bf);

    // attention-weight logits + joint softmax
    gemm_bf16<<<g128, blk, 0, stream>>>(q0, Wawt, b_aw, aw0, NQ, 256, 128, 0);
    gemm_bf16<<<g128, blk, 0, stream>>>(q1, Wawt, b_aw, aw1, NQ, 256, 128, 0);
    joint_softmax<<<(NQ * NHEADS + 255) / 256, 256, 0, stream>>>(aw0, aw1);

    // iter 0
    gemm_bf16<<<g256, blk, 0, stream>>>(f0, Wvt, b_v, bufVb, NQ, 256, 256, 2);
    gemm_bf16<<<g256, blk, 0, stream>>>(q0, Wsot, b_so, bufOff, NQ, 256, 256, 0);
    ms_sample<<<NQ / 8, 256, 0, stream>>>(bufVb, bufOff, aw0, refp, bufO);
    gemm_bf16<<<g256, blk, 0, stream>>>(bufO, Wf0t, bf, out, NQ, 256, 256, 0);

    // iter 1
    gemm_bf16<<<g256, blk, 0, stream>>>(f1, Wvt, b_v, bufVb, NQ, 256, 256, 2);
    gemm_bf16<<<g256, blk, 0, stream>>>(q1, Wsot, b_so, bufOff, NQ, 256, 256, 0);
    ms_sample<<<NQ / 8, 256, 0, stream>>>(bufVb, bufOff, aw1, refp, bufO);
    gemm_bf16<<<g256, blk, 0, stream>>>(bufO, Wf1t, nullptr, out, NQ, 256, 256, 1);
}

// Round 4
// 709.379 us; speedup vs baseline: 2.7126x; 1.3554x over previous
//
#include <hip/hip_runtime.h>
#include <math.h>

#define NBATCH 2
#define LQ     19560
#define LEN    19560              // Len_in == Lq for this problem
#define NQ     (NBATCH * LQ)      // 39120
#define DMODEL 256
#define NHEADS 8
#define HDIM   32
#define NLEV   4
#define NPTS   4

typedef __bf16 bf16x8 __attribute__((ext_vector_type(8)));
typedef float  f32x4  __attribute__((ext_vector_type(4)));
typedef unsigned short ushort_t;

__device__ inline float bf2f(unsigned short u) {
    return __uint_as_float(((unsigned int)u) << 16);
}
__device__ inline unsigned short f2bf(float f) {
    unsigned int u = __float_as_uint(f);
    u += 0x7FFFu + ((u >> 16) & 1u);     // round-to-nearest-even
    return (unsigned short)(u >> 16);
}

// ---------------------------------------------------------------------------
// fp32 -> bf16 bulk convert; 8 elems/thread
// ---------------------------------------------------------------------------
__global__ __launch_bounds__(256) void to_bf16(const float* __restrict__ in,
                                               unsigned short* __restrict__ outp,
                                               int n8)
{
    int i = blockIdx.x * 256 + threadIdx.x;
    if (i >= n8) return;
    float4 x = ((const float4*)in)[i * 2];
    float4 y = ((const float4*)in)[i * 2 + 1];
    union { uint4 u; unsigned short s[8]; } t;
    t.s[0] = f2bf(x.x); t.s[1] = f2bf(x.y); t.s[2] = f2bf(x.z); t.s[3] = f2bf(x.w);
    t.s[4] = f2bf(y.x); t.s[5] = f2bf(y.y); t.s[6] = f2bf(y.z); t.s[7] = f2bf(y.w);
    ((uint4*)outp)[i] = t.u;
}

// ---------------------------------------------------------------------------
// bf16 MFMA GEMM: C[M,N] = A_bf16[M,K] @ Bt_bf16[N,K]^T (+bias)
// 128x128 tile, BK=64, 256 threads = 4 waves (2x2 of 64x64), 4x4 16x16x32 MFMA.
// mode 0: store fp32; mode 1: accumulate fp32; mode 2: store bf16 scattered
//         head-major (n, h, pos, 32) for the sampler.
// ---------------------------------------------------------------------------
#define LDK 72   // padded row stride (bf16): 144 B -> 2-way LDS conflicts (free)

__global__ __launch_bounds__(256) void gemm_bf16(
    const unsigned short* __restrict__ A, const unsigned short* __restrict__ Bt,
    const float* __restrict__ bias, void* __restrict__ Cv,
    int M, int K, int N, int mode)
{
    __shared__ unsigned short As[128 * LDK];
    __shared__ unsigned short Bs[128 * LDK];

    const int tid  = threadIdx.x;
    const int wave = tid >> 6, lane = tid & 63;
    const int wm = wave >> 1, wn = wave & 1;
    const int m0 = blockIdx.y * 128, n0 = blockIdx.x * 128;
    const int lr = lane & 15, quad = lane >> 4;

    const f32x4 zero = {0.f, 0.f, 0.f, 0.f};
    f32x4 acc[4][4];
    #pragma unroll
    for (int i = 0; i < 4; i++)
        #pragma unroll
        for (int j = 0; j < 4; j++) acc[i][j] = zero;

    for (int t = 0; t < K; t += 64) {
        #pragma unroll
        for (int i = 0; i < 4; i++) {
            int v = tid + i * 256;
            int r = v >> 3, c = v & 7;
            int row = m0 + r;
            uint4 d = make_uint4(0, 0, 0, 0);
            if (row < M) d = *(const uint4*)&A[(size_t)row * K + t + c * 8];
            *(uint4*)&As[r * LDK + c * 8] = d;
        }
        #pragma unroll
        for (int i = 0; i < 4; i++) {
            int v = tid + i * 256;
            int r = v >> 3, c = v & 7;
            uint4 d = make_uint4(0, 0, 0, 0);
            if (n0 + r < N) d = *(const uint4*)&Bt[(size_t)(n0 + r) * K + t + c * 8];
            *(uint4*)&Bs[r * LDK + c * 8] = d;
        }
        __syncthreads();

        #pragma unroll
        for (int kk = 0; kk < 2; kk++) {
            bf16x8 af[4], bff[4];
            #pragma unroll
            for (int mi = 0; mi < 4; mi++)
                af[mi] = *(const bf16x8*)&As[(wm * 64 + mi * 16 + lr) * LDK + kk * 32 + quad * 8];
            #pragma unroll
            for (int ni = 0; ni < 4; ni++)
                bff[ni] = *(const bf16x8*)&Bs[(wn * 64 + ni * 16 + lr) * LDK + kk * 32 + quad * 8];
            #pragma unroll
            for (int mi = 0; mi < 4; mi++)
                #pragma unroll
                for (int ni = 0; ni < 4; ni++)
                    acc[mi][ni] = __builtin_amdgcn_mfma_f32_16x16x32_bf16(
                        af[mi], bff[ni], acc[mi][ni], 0, 0, 0);
        }
        __syncthreads();
    }

    float* Cf = (float*)Cv;
    unsigned short* Cb = (unsigned short*)Cv;
    #pragma unroll
    for (int mi = 0; mi < 4; mi++) {
        #pragma unroll
        for (int reg = 0; reg < 4; reg++) {
            int row = m0 + wm * 64 + mi * 16 + quad * 4 + reg;
            if (row >= M) continue;
            #pragma unroll
            for (int ni = 0; ni < 4; ni++) {
                int col = n0 + wn * 64 + ni * 16 + lr;
                float v = acc[mi][ni][reg];
                if (bias) v += bias[col];
                if (mode == 0) {
                    Cf[(size_t)row * N + col] = v;
                } else if (mode == 1) {
                    Cf[(size_t)row * N + col] += v;
                } else {
                    // head-major scatter: (n, h, pos, d)
                    int n = row >= LQ ? 1 : 0;
                    int pos = row - n * LQ;
                    int h = col >> 5, d = col & 31;
                    Cb[((size_t)(n * NHEADS + h) * LEN + pos) * HDIM + d] = f2bf(v);
                }
            }
        }
    }
}

// ---------------------------------------------------------------------------
// Weight transpose+convert: outw[n*K + k] = bf16(in[k*N + n]); K == 256.
// ---------------------------------------------------------------------------
__global__ __launch_bounds__(256) void wt_conv(const float* __restrict__ in,
                                               unsigned short* __restrict__ outw,
                                               int K, int N)
{
    int o = blockIdx.x * 256 + threadIdx.x;  // o = n*K + k
    if (o >= K * N) return;
    int k = o & 255;
    int n = o >> 8;
    outw[o] = f2bf(in[(size_t)k * N + n]);
}

// ---------------------------------------------------------------------------
// Fused tail weights (transposed bf16): Wf_i^T[n][k] = (W_o @ W_agg_half_i)[k][n]
// bf = b_o @ (Wagg0 + Wagg1) + b_agg  (fp32)
// ---------------------------------------------------------------------------
__global__ __launch_bounds__(256) void fuse_weights(
    const float* __restrict__ Wo, const float* __restrict__ Wagg,
    const float* __restrict__ bo, const float* __restrict__ bagg,
    unsigned short* __restrict__ Wf0t, unsigned short* __restrict__ Wf1t,
    float* __restrict__ bf)
{
    int n = threadIdx.x;
    int k = blockIdx.x;
    float s0 = 0.f, s1 = 0.f;
    for (int j = 0; j < 256; j++) {
        float w = Wo[k * 256 + j];
        s0 += w * Wagg[j * 256 + n];
        s1 += w * Wagg[(256 + j) * 256 + n];
    }
    Wf0t[(size_t)n * 256 + k] = f2bf(s0);
    Wf1t[(size_t)n * 256 + k] = f2bf(s1);
    if (k == 0) {
        float b = bagg[n];
        for (int j = 0; j < 256; j++)
            b += bo[j] * (Wagg[j * 256 + n] + Wagg[(256 + j) * 256 + n]);
        bf[n] = b;
    }
}

// ---------------------------------------------------------------------------
// Joint softmax over 32 logits per (n,q,h), in-place
// ---------------------------------------------------------------------------
__global__ __launch_bounds__(256) void joint_softmax(float* __restrict__ aw0,
                                                     float* __restrict__ aw1)
{
    int r = blockIdx.x * 256 + threadIdx.x;
    if (r >= NQ * NHEADS) return;
    int nq = r >> 3, h = r & 7;
    float* p0 = aw0 + (size_t)nq * 128 + h * 16;
    float* p1 = aw1 + (size_t)nq * 128 + h * 16;
    float v[32];
    #pragma unroll
    for (int i = 0; i < 16; i++) { v[i] = p0[i]; v[16 + i] = p1[i]; }
    float m = v[0];
    #pragma unroll
    for (int i = 1; i < 32; i++) m = fmaxf(m, v[i]);
    float s = 0.f;
    #pragma unroll
    for (int i = 0; i < 32; i++) { v[i] = expf(v[i] - m); s += v[i]; }
    float inv = 1.0f / s;
    #pragma unroll
    for (int i = 0; i < 16; i++) { p0[i] = v[i] * inv; p1[i] = v[16 + i] * inv; }
}

// ---------------------------------------------------------------------------
// Deformable sampling, head-major values with XCD affinity.
// val: bf16 (n, h, pos, 32). Block: head = blockIdx.x % 8 (-> XCD h),
// 64 queries/block, 4 lanes/query, lane owns 8 dims (uint4 gathers).
// out: bf16 (NQ, 256), col = h*32+d
// ---------------------------------------------------------------------------
__global__ __launch_bounds__(256) void ms_sample(
    const unsigned short* __restrict__ val, const float* __restrict__ off,
    const float* __restrict__ aw, const float* __restrict__ refp,
    unsigned short* __restrict__ outb)
{
    const int bid   = blockIdx.x;
    const int h     = bid & 7;
    const int qbase = (bid >> 3) << 6;
    const int tid   = threadIdx.x;
    const int ql    = tid >> 2;
    const int dl    = (tid & 3) * 8;
    const int nq    = qbase + ql;
    if (nq >= NQ) return;
    const int n = nq >= LQ ? 1 : 0;

    const int Hs[4] = {92, 46, 23, 12};
    const int Ws[4] = {160, 80, 40, 20};
    const int Ss[4] = {0, 14720, 18400, 19320};

    const unsigned short* vslab = val + (size_t)(n * NHEADS + h) * LEN * HDIM + dl;
    const size_t obase = ((size_t)nq * NHEADS + h) * 16;
    const float* rpq = refp + (size_t)nq * 8;

    float acc[8] = {0.f, 0.f, 0.f, 0.f, 0.f, 0.f, 0.f, 0.f};

    #pragma unroll
    for (int l = 0; l < NLEV; l++) {
        const int H = Hs[l], W = Ws[l];
        const unsigned short* vb = vslab + (size_t)Ss[l] * HDIM;
        const float rx = rpq[l * 2 + 0];
        const float ry = rpq[l * 2 + 1];
        float4 o0 = *(const float4*)&off[(obase + l * 4) * 2];
        float4 o1 = *(const float4*)&off[(obase + l * 4) * 2 + 4];
        float4 a4 = *(const float4*)&aw[obase + l * 4];
        float oxs[4] = {o0.x, o0.z, o1.x, o1.z};
        float oys[4] = {o0.y, o0.w, o1.y, o1.w};
        float avs[4] = {a4.x, a4.y, a4.z, a4.w};
        #pragma unroll
        for (int p = 0; p < NPTS; p++) {
            const float a = avs[p];
            // ref op order: loc = ref + off/normalizer; x = loc*W - 0.5
            const float lx = rx + oxs[p] / (float)W;
            const float ly = ry + oys[p] / (float)H;
            const float x = lx * (float)W - 0.5f;
            const float y = ly * (float)H - 0.5f;
            const float x0f = floorf(x), y0f = floorf(y);
            const int x0 = (int)x0f, y0 = (int)y0f;
            const float wx1 = x - x0f;
            const float wx0 = x0f + 1.0f - x;
            const float wy1 = y - y0f;
            const float wy0 = y0f + 1.0f - y;

            const bool xin0 = (x0 >= 0) && (x0 < W);
            const bool xin1 = (x0 + 1 >= 0) && (x0 + 1 < W);
            const bool yin0 = (y0 >= 0) && (y0 < H);
            const bool yin1 = (y0 + 1 >= 0) && (y0 + 1 < H);

            if (yin0 && xin0) {
                uint4 c = *(const uint4*)(vb + (size_t)(y0 * W + x0) * HDIM);
                const unsigned short* u = (const unsigned short*)&c;
                const float w = a * wy0 * wx0;
                #pragma unroll
                for (int e = 0; e < 8; e++) acc[e] += w * bf2f(u[e]);
            }
            if (yin0 && xin1) {
                uint4 c = *(const uint4*)(vb + (size_t)(y0 * W + x0 + 1) * HDIM);
                const unsigned short* u = (const unsigned short*)&c;
                const float w = a * wy0 * wx1;
                #pragma unroll
                for (int e = 0; e < 8; e++) acc[e] += w * bf2f(u[e]);
            }
            if (yin1 && xin0) {
                uint4 c = *(const uint4*)(vb + (size_t)((y0 + 1) * W + x0) * HDIM);
                const unsigned short* u = (const unsigned short*)&c;
                const float w = a * wy1 * wx0;
                #pragma unroll
                for (int e = 0; e < 8; e++) acc[e] += w * bf2f(u[e]);
            }
            if (yin1 && xin1) {
                uint4 c = *(const uint4*)(vb + (size_t)((y0 + 1) * W + x0 + 1) * HDIM);
                const unsigned short* u = (const unsigned short*)&c;
                const float w = a * wy1 * wx1;
                #pragma unroll
                for (int e = 0; e < 8; e++) acc[e] += w * bf2f(u[e]);
            }
        }
    }
    union { uint4 u; unsigned short s[8]; } t;
    #pragma unroll
    for (int e = 0; e < 8; e++) t.s[e] = f2bf(acc[e]);
    *(uint4*)&outb[(size_t)nq * DMODEL + h * HDIM + dl] = t.u;
}

// ---------------------------------------------------------------------------
extern "C" void kernel_launch(void* const* d_in, const int* in_sizes, int n_in,
                              void* d_out, int out_size, void* d_ws, size_t ws_size,
                              hipStream_t stream)
{
    const float* q0    = (const float*)d_in[0];
    const float* q1    = (const float*)d_in[1];
    const float* refp  = (const float*)d_in[2];
    const float* f0    = (const float*)d_in[3];
    const float* f1    = (const float*)d_in[4];
    const float* W_so  = (const float*)d_in[7];
    const float* b_so  = (const float*)d_in[8];
    const float* W_aw  = (const float*)d_in[9];
    const float* b_aw  = (const float*)d_in[10];
    const float* W_v   = (const float*)d_in[11];
    const float* b_v   = (const float*)d_in[12];
    const float* W_o   = (const float*)d_in[13];
    const float* b_o   = (const float*)d_in[14];
    const float* W_agg = (const float*)d_in[15];
    const float* b_agg = (const float*)d_in[16];
    float* out = (float*)d_out;

    float* ws = (float*)d_ws;
    const size_t C128 = (size_t)NQ * 128;
    unsigned short* bufVb = (unsigned short*)ws;            // NQ*256 bf16
    float* bufOff = ws + C128;                              // NQ*256 fl
    unsigned short* bufOb = (unsigned short*)(bufOff + (size_t)NQ * 256); // NQ*256 bf16
    float* aw0 = (float*)bufOb + C128;                      // NQ*128 fl
    float* aw1 = aw0 + C128;                                // NQ*128 fl
    unsigned short* q0b = (unsigned short*)(aw1 + C128);    // NQ*256 bf16
    unsigned short* q1b = q0b + (size_t)NQ * 256;
    unsigned short* fb  = q1b + (size_t)NQ * 256;
    unsigned short* Wvt  = fb + (size_t)NQ * 256;           // 65536 ush
    unsigned short* Wsot = Wvt  + 65536;
    unsigned short* Wawt = Wsot + 65536;                    // 32768 ush
    unsigned short* Wf0t = Wawt + 32768;
    unsigned short* Wf1t = Wf0t + 65536;
    float* bf = (float*)(Wf1t + 65536);                     // 256 fl

    const int MB = (NQ + 127) / 128;   // 306
    const int N8 = NQ * 256 / 8;       // elems/8 for conversions
    dim3 blk(256);
    dim3 g256(2, MB);
    dim3 g128(1, MB);
    const int sgrid = ((NQ + 63) / 64) * 8;   // 612 chunks x 8 heads

    // conversions + weight preps
    to_bf16<<<(N8 + 255) / 256, 256, 0, stream>>>(q0, q0b, N8);
    to_bf16<<<(N8 + 255) / 256, 256, 0, stream>>>(q1, q1b, N8);
    wt_conv<<<(65536 + 255) / 256, 256, 0, stream>>>(W_v,  Wvt,  256, 256);
    wt_conv<<<(65536 + 255) / 256, 256, 0, stream>>>(W_so, Wsot, 256, 256);
    wt_conv<<<(32768 + 255) / 256, 256, 0, stream>>>(W_aw, Wawt, 256, 128);
    fuse_weights<<<256, 256, 0, stream>>>(W_o, W_agg, b_o, b_agg, Wf0t, Wf1t, bf);

    // attention-weight logits + joint softmax
    gemm_bf16<<<g128, blk, 0, stream>>>(q0b, Wawt, b_aw, aw0, NQ, 256, 128, 0);
    gemm_bf16<<<g128, blk, 0, stream>>>(q1b, Wawt, b_aw, aw1, NQ, 256, 128, 0);
    joint_softmax<<<(NQ * NHEADS + 255) / 256, 256, 0, stream>>>(aw0, aw1);

    // iter 0
    to_bf16<<<(N8 + 255) / 256, 256, 0, stream>>>(f0, fb, N8);
    gemm_bf16<<<g256, blk, 0, stream>>>(fb, Wvt, b_v, bufVb, NQ, 256, 256, 2);
    gemm_bf16<<<g256, blk, 0, stream>>>(q0b, Wsot, b_so, bufOff, NQ, 256, 256, 0);
    ms_sample<<<sgrid, 256, 0, stream>>>(bufVb, bufOff, aw0, refp, bufOb);
    gemm_bf16<<<g256, blk, 0, stream>>>(bufOb, Wf0t, bf, out, NQ, 256, 256, 0);

    // iter 1
    to_bf16<<<(N8 + 255) / 256, 256, 0, stream>>>(f1, fb, N8);
    gemm_bf16<<<g256, blk, 0, stream>>>(fb, Wvt, b_v, bufVb, NQ, 256, 256, 2);
    gemm_bf16<<<g256, blk, 0, stream>>>(q1b, Wsot, b_so, bufOff, NQ, 256, 256, 0);
    ms_sample<<<sgrid, 256, 0, stream>>>(bufVb, bufOff, aw1, refp, bufOb);
    gemm_bf16<<<g256, blk, 0, stream>>>(bufOb, Wf1t, nullptr, out, NQ, 256, 256, 1);
}

// Round 5
// 632.509 us; speedup vs baseline: 3.0423x; 1.1215x over previous
//
#include <hip/hip_runtime.h>
#include <math.h>

#define NBATCH 2
#define LQ     19560
#define LEN    19560
#define NQ     (NBATCH * LQ)      // 39120
#define DMODEL 256
#define NHEADS 8
#define HDIM   32
#define NLEV   4
#define NPTS   4
#define LDQS   384                // QS row stride: [0..255]=offsets, [256..383]=logits/aw

typedef __bf16 bf16x8 __attribute__((ext_vector_type(8)));
typedef float  f32x4  __attribute__((ext_vector_type(4)));

__device__ inline float bf2f(unsigned short u) {
    return __uint_as_float(((unsigned int)u) << 16);
}
__device__ inline unsigned short f2bf(float f) {
    unsigned int u = __float_as_uint(f);
    u += 0x7FFFu + ((u >> 16) & 1u);     // RNE
    return (unsigned short)(u >> 16);
}

// ---------------------------------------------------------------------------
// Batched bf16 MFMA GEMM: C_z = A_z @ Bt^T (+bias), z = blockIdx.z
// A: fp32 (a_bf16=0, converted in staging) or bf16 (a_bf16=1), row stride lda.
// Bt: bf16 [N][K] row stride K. 128x128 tile, BK=64, 4 waves, 4x4 16x16x32 MFMA.
// mode 0: store fp32 at C[row*ldc+col]
// mode 2: store bf16 head-major scatter (n, h, pos, d)  [value tensor]
// ---------------------------------------------------------------------------
#define LDK 72

__global__ __launch_bounds__(256) void gemm_multi(
    const void* __restrict__ A0, const void* __restrict__ A1,
    const unsigned short* __restrict__ Bt, const float* __restrict__ bias,
    void* __restrict__ C0, void* __restrict__ C1,
    int M, int K, int lda, int N, int ldc, int a_bf16, int mode)
{
    __shared__ unsigned short As[128 * LDK];
    __shared__ unsigned short Bs[128 * LDK];

    const int z = blockIdx.z;
    const void* A = z ? A1 : A0;
    void* Cv = z ? C1 : C0;

    const int tid  = threadIdx.x;
    const int wave = tid >> 6, lane = tid & 63;
    const int wm = wave >> 1, wn = wave & 1;
    const int m0 = blockIdx.y * 128, n0 = blockIdx.x * 128;
    const int lr = lane & 15, quad = lane >> 4;

    const f32x4 zero = {0.f, 0.f, 0.f, 0.f};
    f32x4 acc[4][4];
    #pragma unroll
    for (int i = 0; i < 4; i++)
        #pragma unroll
        for (int j = 0; j < 4; j++) acc[i][j] = zero;

    for (int t = 0; t < K; t += 64) {
        #pragma unroll
        for (int i = 0; i < 4; i++) {
            int v = tid + i * 256;
            int r = v >> 3, c = v & 7;
            int row = m0 + r;
            uint4 d = make_uint4(0, 0, 0, 0);
            if (row < M) {
                if (a_bf16) {
                    d = *(const uint4*)&((const unsigned short*)A)[(size_t)row * lda + t + c * 8];
                } else {
                    const float* ap = &((const float*)A)[(size_t)row * lda + t + c * 8];
                    float4 x = *(const float4*)ap;
                    float4 y = *(const float4*)(ap + 4);
                    union { uint4 u; unsigned short s[8]; } tmp;
                    tmp.s[0] = f2bf(x.x); tmp.s[1] = f2bf(x.y);
                    tmp.s[2] = f2bf(x.z); tmp.s[3] = f2bf(x.w);
                    tmp.s[4] = f2bf(y.x); tmp.s[5] = f2bf(y.y);
                    tmp.s[6] = f2bf(y.z); tmp.s[7] = f2bf(y.w);
                    d = tmp.u;
                }
            }
            *(uint4*)&As[r * LDK + c * 8] = d;
        }
        #pragma unroll
        for (int i = 0; i < 4; i++) {
            int v = tid + i * 256;
            int r = v >> 3, c = v & 7;
            uint4 d = make_uint4(0, 0, 0, 0);
            if (n0 + r < N) d = *(const uint4*)&Bt[(size_t)(n0 + r) * K + t + c * 8];
            *(uint4*)&Bs[r * LDK + c * 8] = d;
        }
        __syncthreads();

        #pragma unroll
        for (int kk = 0; kk < 2; kk++) {
            bf16x8 af[4], bff[4];
            #pragma unroll
            for (int mi = 0; mi < 4; mi++)
                af[mi] = *(const bf16x8*)&As[(wm * 64 + mi * 16 + lr) * LDK + kk * 32 + quad * 8];
            #pragma unroll
            for (int ni = 0; ni < 4; ni++)
                bff[ni] = *(const bf16x8*)&Bs[(wn * 64 + ni * 16 + lr) * LDK + kk * 32 + quad * 8];
            #pragma unroll
            for (int mi = 0; mi < 4; mi++)
                #pragma unroll
                for (int ni = 0; ni < 4; ni++)
                    acc[mi][ni] = __builtin_amdgcn_mfma_f32_16x16x32_bf16(
                        af[mi], bff[ni], acc[mi][ni], 0, 0, 0);
        }
        __syncthreads();
    }

    float* Cf = (float*)Cv;
    unsigned short* Cb = (unsigned short*)Cv;
    #pragma unroll
    for (int mi = 0; mi < 4; mi++) {
        #pragma unroll
        for (int reg = 0; reg < 4; reg++) {
            int row = m0 + wm * 64 + mi * 16 + quad * 4 + reg;
            if (row >= M) continue;
            #pragma unroll
            for (int ni = 0; ni < 4; ni++) {
                int col = n0 + wn * 64 + ni * 16 + lr;
                float v = acc[mi][ni][reg];
                if (bias) v += bias[col];
                if (mode == 0) {
                    Cf[(size_t)row * ldc + col] = v;
                } else {
                    int n = row >= LQ ? 1 : 0;
                    int pos = row - n * LQ;
                    int h = col >> 5, d = col & 31;
                    Cb[((size_t)(n * NHEADS + h) * LEN + pos) * HDIM + d] = f2bf(v);
                }
            }
        }
    }
}

// ---------------------------------------------------------------------------
// Weight prep: Wvt[n][k]=bf16(Wv[k][n]); Wsoawt[n][k]: n<256 from W_so, else W_aw.
// bsoaw = [b_so | b_aw] fp32(384).
// ---------------------------------------------------------------------------
__global__ __launch_bounds__(256) void prep_weights(
    const float* __restrict__ Wv, const float* __restrict__ Wso,
    const float* __restrict__ Waw, const float* __restrict__ bso,
    const float* __restrict__ baw, unsigned short* __restrict__ Wvt,
    unsigned short* __restrict__ Wsoawt, float* __restrict__ bsoaw)
{
    int o = blockIdx.x * 256 + threadIdx.x;
    if (o < 65536) {
        int n = o >> 8, k = o & 255;
        Wvt[o] = f2bf(Wv[(size_t)k * 256 + n]);
    } else if (o < 65536 + 98304) {
        int p = o - 65536;
        int n = p >> 8, k = p & 255;
        float v = (n < 256) ? Wso[(size_t)k * 256 + n] : Waw[(size_t)k * 128 + (n - 256)];
        Wsoawt[p] = f2bf(v);
    }
    if (o < 384) bsoaw[o] = (o < 256) ? bso[o] : baw[o - 256];
}

// ---------------------------------------------------------------------------
// Fused tail weights, concatenated K=512: Wfcat[n][k] = bf16((Wo@Wagg0)[k][n]),
// Wfcat[n][256+k] = bf16((Wo@Wagg1)[k][n]); bf = b_o@(Wagg0+Wagg1)+b_agg.
// ---------------------------------------------------------------------------
__global__ __launch_bounds__(256) void fuse_weights(
    const float* __restrict__ Wo, const float* __restrict__ Wagg,
    const float* __restrict__ bo, const float* __restrict__ bagg,
    unsigned short* __restrict__ Wfcat, float* __restrict__ bf)
{
    int n = threadIdx.x;
    int k = blockIdx.x;
    float s0 = 0.f, s1 = 0.f;
    for (int j = 0; j < 256; j++) {
        float w = Wo[k * 256 + j];
        s0 += w * Wagg[j * 256 + n];
        s1 += w * Wagg[(256 + j) * 256 + n];
    }
    Wfcat[(size_t)n * 512 + k]       = f2bf(s0);
    Wfcat[(size_t)n * 512 + 256 + k] = f2bf(s1);
    if (k == 0) {
        float b = bagg[n];
        for (int j = 0; j < 256; j++)
            b += bo[j] * (Wagg[j * 256 + n] + Wagg[(256 + j) * 256 + n]);
        bf[n] = b;
    }
}

// ---------------------------------------------------------------------------
// Joint softmax over 32 logits per (n,q,h): QS cols [256..383], in-place
// ---------------------------------------------------------------------------
__global__ __launch_bounds__(256) void joint_softmax(float* __restrict__ QS0,
                                                     float* __restrict__ QS1)
{
    int r = blockIdx.x * 256 + threadIdx.x;
    if (r >= NQ * NHEADS) return;
    int nq = r >> 3, h = r & 7;
    float* p0 = QS0 + (size_t)nq * LDQS + 256 + h * 16;
    float* p1 = QS1 + (size_t)nq * LDQS + 256 + h * 16;
    float v[32];
    #pragma unroll
    for (int i = 0; i < 16; i++) { v[i] = p0[i]; v[16 + i] = p1[i]; }
    float m = v[0];
    #pragma unroll
    for (int i = 1; i < 32; i++) m = fmaxf(m, v[i]);
    float s = 0.f;
    #pragma unroll
    for (int i = 0; i < 32; i++) { v[i] = expf(v[i] - m); s += v[i]; }
    float inv = 1.0f / s;
    #pragma unroll
    for (int i = 0; i < 16; i++) { p0[i] = v[i] * inv; p1[i] = v[16 + i] * inv; }
}

// ---------------------------------------------------------------------------
// Merged deformable sampling (both iters). bid = it*4896 + chunk*8 + head:
// head = XCD affinity (blockIdx % 8), iter in high bits (temporal phasing).
// 64 queries/block, 4 lanes/query, lane owns 8 dims. Writes Ocat (NQ,512) bf16.
// ---------------------------------------------------------------------------
__global__ __launch_bounds__(256) void ms_sample(
    const unsigned short* __restrict__ V0, const unsigned short* __restrict__ V1,
    const float* __restrict__ QS0, const float* __restrict__ QS1,
    const float* __restrict__ refp, unsigned short* __restrict__ Ocat)
{
    int b = blockIdx.x;
    const int it = (b >= 4896) ? 1 : 0;
    b -= it * 4896;
    const int h     = b & 7;
    const int qbase = (b >> 3) << 6;
    const int tid   = threadIdx.x;
    const int ql    = tid >> 2;
    const int dl    = (tid & 3) * 8;
    const int nq    = qbase + ql;
    if (nq >= NQ) return;
    const int n = nq >= LQ ? 1 : 0;

    const unsigned short* val = it ? V1 : V0;
    const float* QS = it ? QS1 : QS0;

    const int Hs[4] = {92, 46, 23, 12};
    const int Ws[4] = {160, 80, 40, 20};
    const int Ss[4] = {0, 14720, 18400, 19320};

    const unsigned short* vslab = val + (size_t)(n * NHEADS + h) * LEN * HDIM + dl;
    const float* offrow = QS + (size_t)nq * LDQS;           // cols 0..255
    const float* awrow  = offrow + 256 + h * 16;            // cols 256..383
    const float* rpq = refp + (size_t)nq * 8;

    float acc[8] = {0.f, 0.f, 0.f, 0.f, 0.f, 0.f, 0.f, 0.f};

    #pragma unroll
    for (int l = 0; l < NLEV; l++) {
        const int H = Hs[l], W = Ws[l];
        const unsigned short* vb = vslab + (size_t)Ss[l] * HDIM;
        const float rx = rpq[l * 2 + 0];
        const float ry = rpq[l * 2 + 1];
        float4 o0 = *(const float4*)&offrow[(h * 16 + l * 4) * 2];
        float4 o1 = *(const float4*)&offrow[(h * 16 + l * 4) * 2 + 4];
        float4 a4 = *(const float4*)&awrow[l * 4];
        float oxs[4] = {o0.x, o0.z, o1.x, o1.z};
        float oys[4] = {o0.y, o0.w, o1.y, o1.w};
        float avs[4] = {a4.x, a4.y, a4.z, a4.w};
        #pragma unroll
        for (int p = 0; p < NPTS; p++) {
            const float a = avs[p];
            const float lx = rx + oxs[p] / (float)W;
            const float ly = ry + oys[p] / (float)H;
            const float x = lx * (float)W - 0.5f;
            const float y = ly * (float)H - 0.5f;
            const float x0f = floorf(x), y0f = floorf(y);
            const int x0 = (int)x0f, y0 = (int)y0f;
            const float wx1 = x - x0f;
            const float wx0 = x0f + 1.0f - x;
            const float wy1 = y - y0f;
            const float wy0 = y0f + 1.0f - y;

            const bool xin0 = (x0 >= 0) && (x0 < W);
            const bool xin1 = (x0 + 1 >= 0) && (x0 + 1 < W);
            const bool yin0 = (y0 >= 0) && (y0 < H);
            const bool yin1 = (y0 + 1 >= 0) && (y0 + 1 < H);

            if (yin0 && xin0) {
                uint4 c = *(const uint4*)(vb + (size_t)(y0 * W + x0) * HDIM);
                const unsigned short* u = (const unsigned short*)&c;
                const float w = a * wy0 * wx0;
                #pragma unroll
                for (int e = 0; e < 8; e++) acc[e] += w * bf2f(u[e]);
            }
            if (yin0 && xin1) {
                uint4 c = *(const uint4*)(vb + (size_t)(y0 * W + x0 + 1) * HDIM);
                const unsigned short* u = (const unsigned short*)&c;
                const float w = a * wy0 * wx1;
                #pragma unroll
                for (int e = 0; e < 8; e++) acc[e] += w * bf2f(u[e]);
            }
            if (yin1 && xin0) {
                uint4 c = *(const uint4*)(vb + (size_t)((y0 + 1) * W + x0) * HDIM);
                const unsigned short* u = (const unsigned short*)&c;
                const float w = a * wy1 * wx0;
                #pragma unroll
                for (int e = 0; e < 8; e++) acc[e] += w * bf2f(u[e]);
            }
            if (yin1 && xin1) {
                uint4 c = *(const uint4*)(vb + (size_t)((y0 + 1) * W + x0 + 1) * HDIM);
                const unsigned short* u = (const unsigned short*)&c;
                const float w = a * wy1 * wx1;
                #pragma unroll
                for (int e = 0; e < 8; e++) acc[e] += w * bf2f(u[e]);
            }
        }
    }
    union { uint4 u; unsigned short s[8]; } t;
    #pragma unroll
    for (int e = 0; e < 8; e++) t.s[e] = f2bf(acc[e]);
    *(uint4*)&Ocat[(size_t)nq * 512 + it * 256 + h * HDIM + dl] = t.u;
}

// ---------------------------------------------------------------------------
extern "C" void kernel_launch(void* const* d_in, const int* in_sizes, int n_in,
                              void* d_out, int out_size, void* d_ws, size_t ws_size,
                              hipStream_t stream)
{
    const float* q0    = (const float*)d_in[0];
    const float* q1    = (const float*)d_in[1];
    const float* refp  = (const float*)d_in[2];
    const float* f0    = (const float*)d_in[3];
    const float* f1    = (const float*)d_in[4];
    const float* W_so  = (const float*)d_in[7];
    const float* b_so  = (const float*)d_in[8];
    const float* W_aw  = (const float*)d_in[9];
    const float* b_aw  = (const float*)d_in[10];
    const float* W_v   = (const float*)d_in[11];
    const float* b_v   = (const float*)d_in[12];
    const float* W_o   = (const float*)d_in[13];
    const float* b_o   = (const float*)d_in[14];
    const float* W_agg = (const float*)d_in[15];
    const float* b_agg = (const float*)d_in[16];
    float* out = (float*)d_out;

    float* ws = (float*)d_ws;
    float* QS0 = ws;                                        // NQ*384 fp32
    float* QS1 = QS0 + (size_t)NQ * LDQS;                   // NQ*384 fp32
    unsigned short* V0   = (unsigned short*)(QS1 + (size_t)NQ * LDQS);  // NQ*256 bf16
    unsigned short* V1   = V0 + (size_t)NQ * 256;
    unsigned short* Ocat = V1 + (size_t)NQ * 256;           // NQ*512 bf16
    unsigned short* Wvt    = Ocat + (size_t)NQ * 512;       // 65536
    unsigned short* Wsoawt = Wvt + 65536;                   // 98304
    unsigned short* Wfcat  = Wsoawt + 98304;                // 131072
    float* bsoaw = (float*)(Wfcat + 131072);                // 384
    float* bf    = bsoaw + 384;                             // 256

    const int MB = (NQ + 127) / 128;   // 306
    dim3 blk(256);

    prep_weights<<<640, blk, 0, stream>>>(W_v, W_so, W_aw, b_so, b_aw, Wvt, Wsoawt, bsoaw);
    fuse_weights<<<256, blk, 0, stream>>>(W_o, W_agg, b_o, b_agg, Wfcat, bf);

    // q-side: offsets + logits for both iters in one batched GEMM
    gemm_multi<<<dim3(3, MB, 2), blk, 0, stream>>>(
        q0, q1, Wsoawt, bsoaw, QS0, QS1, NQ, 256, 256, 384, LDQS, 0, 0);

    joint_softmax<<<(NQ * NHEADS + 255) / 256, blk, 0, stream>>>(QS0, QS1);

    // values for both iters, head-major scatter
    gemm_multi<<<dim3(2, MB, 2), blk, 0, stream>>>(
        f0, f1, Wvt, b_v, V0, V1, NQ, 256, 256, 256, 256, 0, 2);

    // merged sampler (both iters) -> Ocat
    ms_sample<<<2 * ((NQ + 63) / 64) * 8, blk, 0, stream>>>(V0, V1, QS0, QS1, refp, Ocat);

    // single K=512 tail GEMM -> out
    gemm_multi<<<dim3(2, MB, 1), blk, 0, stream>>>(
        Ocat, Ocat, Wfcat, bf, out, out, NQ, 512, 512, 256, 256, 1, 0);
}